// Round 17
// baseline (536.408 us; speedup 1.0000x reference)
//
#include <hip/hip_runtime.h>

#define TSTEPS 1023
#define GAMMA  (0.01f / 32.0f)   // LR * dL/dy scale: 2/(64*2) folded
#define EPSV   1e-5f

typedef float v2f __attribute__((ext_vector_type(2)));
typedef unsigned int v2u __attribute__((ext_vector_type(2)));

template<int CTRL>
__device__ __forceinline__ float dppmov(float x) {
    return __int_as_float(__builtin_amdgcn_update_dpp(0, __float_as_int(x), CTRL, 0xF, 0xF, true));
}
__device__ __forceinline__ v2u swap16(float a, float b) {
    return __builtin_amdgcn_permlane16_swap(__float_as_uint(a), __float_as_uint(b), false, false);
}
__device__ __forceinline__ v2u swap32(float a, float b) {
    return __builtin_amdgcn_permlane32_swap(__float_as_uint(a), __float_as_uint(b), false, false);
}
#define U2F(x) __uint_as_float(x)

// scalar view of packed v2f array
#define PV(arr, j) (((j) & 1) ? arr[(j) >> 1].y : arr[(j) >> 1].x)

// ---------------- single fused kernel: per-block prep + per-batch TTT scan ----------------
// Each of the 256 blocks (1 wave) redundantly computes the token-table prep
// (hs = LN(FFN(embed)), Gs = gamma*(hs hs^T)+gamma, Z0 = hs@w1+b1) before its
// scan. Rationale: prep as separate kernels cost 77us of wall (2 launches +
// gaps + latency-bound tiny kernels); redundant in-block prep costs ~18K
// instrs ~= 30us at the measured 4cyc/instr wave cadence. Single launch.
// Prep layout: lane = token (all FFN/LN sums in-lane, no cross-lane ops);
// ffw1/ffw2 streamed through an LDS overlay of the (not-yet-live) hs/Gs
// region; aux vectors in a dedicated region. Scan = R16 verbatim.
struct TTTSmem {
    float hs[4096];               // prep phase: holds ffw1 then ffw2 (8192 floats spans hs+Gs)
    float Gs[4096];
    int   sq[2048];               // unguarded prefetch reads sq[2048..2049] -> lands in aux (harmless)
    float aux[1360];              // w1[0,1024) b1[1024,1040) lng[1040,1104) lnb[1104,1168) ffb1[1168,1296) ffb2[1296,1360)
    __align__(16) float Z[64 * 20 + 8];
    float ctx[64];
};

__launch_bounds__(64, 1)
__global__ void ttt_kernel(const int* __restrict__ seq,   const float* __restrict__ embed,
                           const float* __restrict__ ffw1, const float* __restrict__ ffb1,
                           const float* __restrict__ ffw2, const float* __restrict__ ffb2,
                           const float* __restrict__ lng,  const float* __restrict__ lnb,
                           const float* __restrict__ w1g,  const float* __restrict__ b1g,
                           const float* __restrict__ w2,   const float* __restrict__ b2i,
                           const float* __restrict__ outw, const float* __restrict__ outb,
                           float* __restrict__ out) {
    __shared__ TTTSmem sm;

    const int b    = blockIdx.x;
    const int lane = threadIdx.x;

    const int P = ((lane & 1) << 3) | ((lane & 2) << 1);   // 8*b0 + 4*b1
    const int K = ((lane & 1) << 1) | ((lane >> 1) & 1);   // 2*b0 + b1 (chunk xor)
    const int ro0 = (0 ^ K) << 2;
    const int ro1 = (1 ^ K) << 2;
    const int ro2 = (2 ^ K) << 2;
    const int ro3 = (3 ^ K) << 2;

    float* const WR = sm.hs;      // 8192-float weight overlay (hs+Gs, dead until hs written)
    float* const AX = sm.aux;

    // ================= PREP (single wave: in-order DS, no barriers needed) =================
    {   // stage aux (w1, b1, lng, lnb, ffb1, ffb2) and ffw1 (into overlay)
        float4*       ax4 = (float4*)AX;
        const float4* sw1 = (const float4*)w1g;
#pragma unroll
        for (int m = 0; m < 4; ++m) ax4[m * 64 + lane] = sw1[m * 64 + lane];
        if (lane < 4)  ax4[256 + lane] = ((const float4*)b1g)[lane];
        if (lane < 16) ax4[260 + lane] = ((const float4*)lng)[lane];
        if (lane < 16) ax4[276 + lane] = ((const float4*)lnb)[lane];
        if (lane < 32) ax4[292 + lane] = ((const float4*)ffb1)[lane];
        if (lane < 16) ax4[324 + lane] = ((const float4*)ffb2)[lane];
        float4*       wr4 = (float4*)WR;
        const float4* s1  = (const float4*)ffw1;
#pragma unroll
        for (int m = 0; m < 32; ++m) wr4[m * 64 + lane] = s1[m * 64 + lane];
    }

    // ---- a1 = e @ ffw1 + ffb1 (pre-relu), lane = token, a1 in regs ----
    v2f a1_2[64];
    {
        const float4* fb1 = (const float4*)(AX + 1168);
#pragma unroll
        for (int c = 0; c < 32; ++c) {
            float4 v = fb1[c];
            a1_2[2 * c]     = (v2f){v.x, v.y};
            a1_2[2 * c + 1] = (v2f){v.z, v.w};
        }
        const float* erow = embed + lane * 64;
#pragma unroll 4
        for (int x = 0; x < 64; ++x) {
            const float ex = erow[x];
            const v2f exx = {ex, ex};
            const float4* wrow = (const float4*)(WR + x * 128);
#pragma unroll
            for (int c = 0; c < 32; ++c) {
                float4 wv = wrow[c];
                a1_2[2 * c]     += (v2f){wv.x, wv.y} * exx;
                a1_2[2 * c + 1] += (v2f){wv.z, wv.w} * exx;
            }
        }
    }

    {   // stage ffw2 over the same overlay (ffw1 reads all done; in-order DS)
        float4*       wr4 = (float4*)WR;
        const float4* s2  = (const float4*)ffw2;
#pragma unroll
        for (int m = 0; m < 32; ++m) wr4[m * 64 + lane] = s2[m * 64 + lane];
    }

    // ---- h = e + ffb2 + relu(a1) @ ffw2 ----
    v2f h2[32];
    {
        const float4* erow4 = (const float4*)(embed + lane * 64);
        const float4* fb2   = (const float4*)(AX + 1296);
#pragma unroll
        for (int c = 0; c < 16; ++c) {
            float4 ev = erow4[c];
            float4 bv = fb2[c];
            h2[2 * c]     = (v2f){ev.x + bv.x, ev.y + bv.y};
            h2[2 * c + 1] = (v2f){ev.z + bv.z, ev.w + bv.w};
        }
    }
#pragma unroll
    for (int i = 0; i < 128; ++i) {
        const float ai = fmaxf(PV(a1_2, i), 0.0f);
        const v2f aii = {ai, ai};
        const float4* wrow = (const float4*)(WR + i * 64);
#pragma unroll
        for (int c = 0; c < 16; ++c) {
            float4 wv = wrow[c];
            h2[2 * c]     += (v2f){wv.x, wv.y} * aii;
            h2[2 * c + 1] += (v2f){wv.z, wv.w} * aii;
        }
    }

    // ---- LayerNorm (in-lane) -> hsr2 = hs row `lane` in regs ----
    v2f hsr2[32];
    {
        v2f s = {0.0f, 0.0f};
#pragma unroll
        for (int k = 0; k < 32; ++k) s += h2[k];
        const float mu = (s.x + s.y) * (1.0f / 64.0f);
        const v2f mu2 = {mu, mu};
        v2f vs = {0.0f, 0.0f};
#pragma unroll
        for (int k = 0; k < 32; ++k) { v2f dv = h2[k] - mu2; vs += dv * dv; }
        const float rstd = 1.0f / sqrtf((vs.x + vs.y) * (1.0f / 64.0f) + EPSV);
        const v2f r2 = {rstd, rstd};
        const float4* lg4 = (const float4*)(AX + 1040);
        const float4* lb4 = (const float4*)(AX + 1104);
#pragma unroll
        for (int c = 0; c < 16; ++c) {
            float4 gv = lg4[c], bv = lb4[c];
            hsr2[2 * c]     = (h2[2 * c]     - mu2) * r2 * (v2f){gv.x, gv.y} + (v2f){bv.x, bv.y};
            hsr2[2 * c + 1] = (h2[2 * c + 1] - mu2) * r2 * (v2f){gv.z, gv.w} + (v2f){bv.z, bv.w};
        }
    }
    {   // write hs row `lane` (overlay now dead); one-time conflicted writes, off-chain
        float4* hrow = (float4*)(sm.hs + lane * 64);
#pragma unroll
        for (int c = 0; c < 16; ++c)
            hrow[c] = make_float4(hsr2[2 * c].x, hsr2[2 * c].y, hsr2[2 * c + 1].x, hsr2[2 * c + 1].y);
    }

    // ---- Gram: Gs[w*64 + lane] = gamma*dot(hs_w, hs_lane) + gamma ----
#pragma unroll 1
    for (int w = 0; w < 64; ++w) {
        const float4* hw = (const float4*)(sm.hs + w * 64);   // uniform addr -> broadcast reads
        v2f acc = {0.0f, 0.0f};
#pragma unroll
        for (int c = 0; c < 16; ++c) {
            float4 hv = hw[c];
            acc += (v2f){hv.x, hv.y} * hsr2[2 * c];
            acc += (v2f){hv.z, hv.w} * hsr2[2 * c + 1];
        }
        sm.Gs[w * 64 + lane] = GAMMA * (acc.x + acc.y) + GAMMA;
    }

    // ---- Z0 row `lane` = hs_lane @ w1 + b1 -> sm.Z (logical order) ----
    {
        v2f z0[8];
        const float4* b14 = (const float4*)(AX + 1024);
#pragma unroll
        for (int c = 0; c < 4; ++c) {
            float4 v = b14[c];
            z0[2 * c]     = (v2f){v.x, v.y};
            z0[2 * c + 1] = (v2f){v.z, v.w};
        }
#pragma unroll
        for (int k = 0; k < 32; ++k) {
            const v2f va = {hsr2[k].x, hsr2[k].x};
            const v2f vb = {hsr2[k].y, hsr2[k].y};
            const float4* w1a = (const float4*)(AX + (2 * k) * 16);
            const float4* w1b = (const float4*)(AX + (2 * k + 1) * 16);
#pragma unroll
            for (int c = 0; c < 4; ++c) {
                float4 wv = w1a[c];
                z0[2 * c]     += (v2f){wv.x, wv.y} * va;
                z0[2 * c + 1] += (v2f){wv.z, wv.w} * va;
                float4 uv = w1b[c];
                z0[2 * c]     += (v2f){uv.x, uv.y} * vb;
                z0[2 * c + 1] += (v2f){uv.z, uv.w} * vb;
            }
        }
        float4* zr = (float4*)(sm.Z + lane * 20);
        zr[0] = make_float4(z0[0].x, z0[0].y, z0[1].x, z0[1].y);
        zr[1] = make_float4(z0[2].x, z0[2].y, z0[3].x, z0[3].y);
        zr[2] = make_float4(z0[4].x, z0[4].y, z0[5].x, z0[5].y);
        zr[3] = make_float4(z0[6].x, z0[6].y, z0[7].x, z0[7].y);
    }

    {   // stage this batch's tokens
        int4*       qv = (int4*)sm.sq;
        const int4* qs = (const int4*)(seq + b * 2048);
#pragma unroll
        for (int m = 0; m < 8; ++m) qv[m * 64 + lane] = qs[m * 64 + lane];
    }

    // ================= SCAN (R16 verbatim) =================
    v2f W2p[8], z2[8];
#pragma unroll
    for (int i = 0; i < 8; ++i) {
        const int m = (2 * i) ^ P;
        v2f w;
        w.x = w2[m * 64 + lane];
        w.y = w2[(m + 1) * 64 + lane];
        W2p[i] = w;
    }
    float b2v = b2i[lane];

    float4 ZrQ[4];
    v2f* Zv = (v2f*)ZrQ;
    {
        const float* zb = sm.Z + lane * 20;
        ZrQ[0] = *(const float4*)(zb + ro0);
        ZrQ[1] = *(const float4*)(zb + ro1);
        ZrQ[2] = *(const float4*)(zb + ro2);
        ZrQ[3] = *(const float4*)(zb + ro3);
    }
    int tk = sm.sq[0];
    {
        const float* zb = sm.Z + tk * 20;
        const float4 c0 = *(const float4*)(zb + ro0);
        const float4 c1 = *(const float4*)(zb + ro1);
        const float4 c2 = *(const float4*)(zb + ro2);
        const float4 c3 = *(const float4*)(zb + ro3);
        z2[0] = {c0.x, c0.y}; z2[1] = {c0.z, c0.w};
        z2[2] = {c1.x, c1.y}; z2[3] = {c1.z, c1.w};
        z2[4] = {c2.x, c2.y}; z2[5] = {c2.z, c2.w};
        z2[6] = {c3.x, c3.y}; z2[7] = {c3.z, c3.w};
    }
    float vv = sm.hs[sm.sq[1] * 64 + lane];

    float4* const wp0 = (float4*)(sm.Z + lane * 20 + ro0);
    float4* const wp1 = (float4*)(sm.Z + lane * 20 + ro1);
    float4* const wp2 = (float4*)(sm.Z + lane * 20 + ro2);
    float4* const wp3 = (float4*)(sm.Z + lane * 20 + ro3);

    int2 pairT  = *(const int2*)(sm.sq + 2);
    int2 pairT1 = *(const int2*)(sm.sq + 4);

#pragma unroll 2
    for (int t = 0; t < TSTEPS - 1; ++t) {
        const int tkn = pairT.x;
        const int tvn = pairT.y;

        const float* zb = sm.Z + tkn * 20;
        const float4 e0 = *(const float4*)(zb + ro0);
        const float4 e1 = *(const float4*)(zb + ro1);
        const float4 e2 = *(const float4*)(zb + ro2);
        const float4 e3 = *(const float4*)(zb + ro3);
        const float vnext = sm.hs[tvn * 64 + lane];
        const float cr = sm.Gs[tk * 64 + lane];
        const float cz = sm.Gs[tk * 64 + tkn];
        const int2 pairT2 = *(const int2*)(sm.sq + 2 * t + 6);  // t=1021 reads aux: unused

        const v2f zero2 = {0.0f, 0.0f};
        v2f a2[8];
#pragma unroll
        for (int i = 0; i < 8; ++i) a2[i] = __builtin_elementwise_max(z2[i], zero2);
        v2f acc0 = a2[0] * W2p[0] + a2[1] * W2p[1];
        v2f acc1 = a2[2] * W2p[2] + a2[3] * W2p[3];
        v2f acc2 = a2[4] * W2p[4] + a2[5] * W2p[5];
        v2f acc3 = a2[6] * W2p[6] + a2[7] * W2p[7];
        v2f accv = (acc0 + acc1) + (acc2 + acc3);
        const float y = b2v + accv.x + accv.y;
        const float d = y - vv;

        const v2f d2 = {d, d};
        v2f p2[8];
#pragma unroll
        for (int i = 0; i < 8; ++i) p2[i] = W2p[i] * d2;
        const float sd = GAMMA * d;
        const v2f sd2 = {sd, sd};
        b2v -= sd;
#pragma unroll
        for (int i = 0; i < 8; ++i) W2p[i] = W2p[i] - sd2 * a2[i];

        float q[8];
#pragma unroll
        for (int j = 0; j < 8; ++j)
            q[j] = PV(p2, j) + dppmov<0xB1>(PV(p2, j + 8));
        float r[4];
#pragma unroll
        for (int j = 0; j < 4; ++j)
            r[j] = q[j] + dppmov<0x4E>(q[j + 4]);

        float rm[4];
        rm[0] = (a2[0].x > 0.0f) ? r[0] : 0.0f;
        rm[1] = (a2[0].y > 0.0f) ? r[1] : 0.0f;
        rm[2] = (a2[1].x > 0.0f) ? r[2] : 0.0f;
        rm[3] = (a2[1].y > 0.0f) ? r[3] : 0.0f;

#pragma unroll
        for (int j = 0; j < 4; ++j) {
            rm[j] = rm[j] + dppmov<0x124>(rm[j]);
            rm[j] = rm[j] + dppmov<0x128>(rm[j]);
        }

        v2u f01 = swap16(rm[0], rm[1]);
        const float F  = U2F(f01[0]) + U2F(f01[1]);
        v2u f23 = swap16(rm[2], rm[3]);
        const float F2 = U2F(f23[0]) + U2F(f23[1]);
        v2u g01 = swap32(F, F2);
        const float T  = U2F(g01[0]) + U2F(g01[1]);
        v2u u01 = swap16(T, T);
        const float U0 = U2F(u01[0]);
        const float U1 = U2F(u01[1]);
        v2u v02 = swap32(U0, U0);
        v2u v13 = swap32(U1, U1);
        const float D0 = U2F(v02[0]);
        const float D2 = U2F(v02[1]);
        const float D1 = U2F(v13[0]);
        const float D3 = U2F(v13[1]);

        float dzs[16];
        dzs[0] = D0; dzs[1] = D1; dzs[2] = D2; dzs[3] = D3;
        dzs[4]  = dppmov<0x4E>(D0); dzs[5]  = dppmov<0x4E>(D1);
        dzs[6]  = dppmov<0x4E>(D2); dzs[7]  = dppmov<0x4E>(D3);
        dzs[8]  = dppmov<0xB1>(D0); dzs[9]  = dppmov<0xB1>(D1);
        dzs[10] = dppmov<0xB1>(D2); dzs[11] = dppmov<0xB1>(D3);
        dzs[12] = dppmov<0x1B>(D0); dzs[13] = dppmov<0x1B>(D1);
        dzs[14] = dppmov<0x1B>(D2); dzs[15] = dppmov<0x1B>(D3);

        v2f dz2[8];
#pragma unroll
        for (int i = 0; i < 8; ++i) dz2[i] = {dzs[2 * i], dzs[2 * i + 1]};

        const v2f cr2 = {cr, cr}, cz2 = {cz, cz};
        const v2f zq2[8] = { {e0.x, e0.y}, {e0.z, e0.w}, {e1.x, e1.y}, {e1.z, e1.w},
                             {e2.x, e2.y}, {e2.z, e2.w}, {e3.x, e3.y}, {e3.z, e3.w} };
#pragma unroll
        for (int i = 0; i < 8; ++i) {
            Zv[i]  = Zv[i]  - cr2 * dz2[i];
            z2[i]  = zq2[i] - cz2 * dz2[i];
        }
        *wp0 = ZrQ[0];
        *wp1 = ZrQ[1];
        *wp2 = ZrQ[2];
        *wp3 = ZrQ[3];

        vv = vnext;
        tk = tkn;
        pairT = pairT1;
        pairT1 = pairT2;
    }

    // ---- peeled final step (t = 1022): tkn = query token sq[2047] ----
    {
        const int tkn = pairT.y;
        const float* zb = sm.Z + tkn * 20;
        const float4 e0 = *(const float4*)(zb + ro0);
        const float4 e1 = *(const float4*)(zb + ro1);
        const float4 e2 = *(const float4*)(zb + ro2);
        const float4 e3 = *(const float4*)(zb + ro3);
        const float cz = sm.Gs[tk * 64 + tkn];

        const v2f zero2 = {0.0f, 0.0f};
        v2f a2[8];
#pragma unroll
        for (int i = 0; i < 8; ++i) a2[i] = __builtin_elementwise_max(z2[i], zero2);
        v2f acc0 = a2[0] * W2p[0] + a2[1] * W2p[1];
        v2f acc1 = a2[2] * W2p[2] + a2[3] * W2p[3];
        v2f acc2 = a2[4] * W2p[4] + a2[5] * W2p[5];
        v2f acc3 = a2[6] * W2p[6] + a2[7] * W2p[7];
        v2f accv = (acc0 + acc1) + (acc2 + acc3);
        const float y = b2v + accv.x + accv.y;
        const float d = y - vv;

        const v2f d2 = {d, d};
        v2f p2[8];
#pragma unroll
        for (int i = 0; i < 8; ++i) p2[i] = W2p[i] * d2;
        const float sd = GAMMA * d;
        const v2f sd2 = {sd, sd};
        b2v -= sd;
#pragma unroll
        for (int i = 0; i < 8; ++i) W2p[i] = W2p[i] - sd2 * a2[i];

        float q[8];
#pragma unroll
        for (int j = 0; j < 8; ++j)
            q[j] = PV(p2, j) + dppmov<0xB1>(PV(p2, j + 8));
        float r[4];
#pragma unroll
        for (int j = 0; j < 4; ++j)
            r[j] = q[j] + dppmov<0x4E>(q[j + 4]);
        float rm[4];
        rm[0] = (a2[0].x > 0.0f) ? r[0] : 0.0f;
        rm[1] = (a2[0].y > 0.0f) ? r[1] : 0.0f;
        rm[2] = (a2[1].x > 0.0f) ? r[2] : 0.0f;
        rm[3] = (a2[1].y > 0.0f) ? r[3] : 0.0f;
#pragma unroll
        for (int j = 0; j < 4; ++j) {
            rm[j] = rm[j] + dppmov<0x124>(rm[j]);
            rm[j] = rm[j] + dppmov<0x128>(rm[j]);
        }
        v2u f01 = swap16(rm[0], rm[1]);
        const float F  = U2F(f01[0]) + U2F(f01[1]);
        v2u f23 = swap16(rm[2], rm[3]);
        const float F2 = U2F(f23[0]) + U2F(f23[1]);
        v2u g01 = swap32(F, F2);
        const float T  = U2F(g01[0]) + U2F(g01[1]);
        v2u u01 = swap16(T, T);
        const float U0 = U2F(u01[0]);
        const float U1 = U2F(u01[1]);
        v2u v02 = swap32(U0, U0);
        v2u v13 = swap32(U1, U1);
        const float D0 = U2F(v02[0]);
        const float D2 = U2F(v02[1]);
        const float D1 = U2F(v13[0]);
        const float D3 = U2F(v13[1]);

        float dzs[16];
        dzs[0] = D0; dzs[1] = D1; dzs[2] = D2; dzs[3] = D3;
        dzs[4]  = dppmov<0x4E>(D0); dzs[5]  = dppmov<0x4E>(D1);
        dzs[6]  = dppmov<0x4E>(D2); dzs[7]  = dppmov<0x4E>(D3);
        dzs[8]  = dppmov<0xB1>(D0); dzs[9]  = dppmov<0xB1>(D1);
        dzs[10] = dppmov<0xB1>(D2); dzs[11] = dppmov<0xB1>(D3);
        dzs[12] = dppmov<0x1B>(D0); dzs[13] = dppmov<0x1B>(D1);
        dzs[14] = dppmov<0x1B>(D2); dzs[15] = dppmov<0x1B>(D3);

        const v2f cz2 = {cz, cz};
        const v2f zq2[8] = { {e0.x, e0.y}, {e0.z, e0.w}, {e1.x, e1.y}, {e1.z, e1.w},
                             {e2.x, e2.y}, {e2.z, e2.w}, {e3.x, e3.y}, {e3.z, e3.w} };
#pragma unroll
        for (int i = 0; i < 8; ++i) {
            v2f dzi = {dzs[2 * i], dzs[2 * i + 1]};
            z2[i] = zq2[i] - cz2 * dzi;
        }
    }

    // ---- final eval: ctx = relu(z_final)@W2_f + b2_f ----
    {
        const v2f zero2 = {0.0f, 0.0f};
        v2f acc = {0.0f, 0.0f};
#pragma unroll
        for (int i = 0; i < 8; ++i)
            acc = acc + __builtin_elementwise_max(z2[i], zero2) * W2p[i];
        sm.ctx[lane] = b2v + acc.x + acc.y;
    }
    __syncthreads();

    float o = outb[lane];
    for (int hh = 0; hh < 64; ++hh) o += sm.ctx[hh] * outw[hh * 64 + lane];
    out[b * 64 + lane] = o;
}

// ---------------- launcher: ONE kernel ----------------
extern "C" void kernel_launch(void* const* d_in, const int* in_sizes, int n_in,
                              void* d_out, int out_size, void* d_ws, size_t ws_size,
                              hipStream_t stream) {
    const int*   seq   = (const int*)d_in[0];
    const float* embed = (const float*)d_in[1];
    const float* ffw1  = (const float*)d_in[2];
    const float* ffb1  = (const float*)d_in[3];
    const float* ffw2  = (const float*)d_in[4];
    const float* ffb2  = (const float*)d_in[5];
    const float* lng   = (const float*)d_in[6];
    const float* lnb   = (const float*)d_in[7];
    const float* w1    = (const float*)d_in[8];
    const float* b1    = (const float*)d_in[9];
    const float* w2    = (const float*)d_in[10];
    const float* b2    = (const float*)d_in[11];
    const float* outw  = (const float*)d_in[12];
    const float* outb  = (const float*)d_in[13];
    float* out = (float*)d_out;

    hipLaunchKernelGGL(ttt_kernel, dim3(256), dim3(64), 0, stream,
                       seq, embed, ffw1, ffb1, ffw2, ffb2, lng, lnb,
                       w1, b1, w2, b2, outw, outb, out);
}

// Round 18
// 431.766 us; speedup vs baseline: 1.2424x; 1.2424x over previous
//
#include <hip/hip_runtime.h>

#define TSTEPS 1023
#define GAMMA  (0.01f / 32.0f)   // LR * dL/dy scale: 2/(64*2) folded
#define EPSV   1e-5f

// workspace layout (float offsets)
#define WS_HS 0       // 64*64 hs table
#define WS_G  4096    // 64*64 PRE-SCALED gram: Gs = GAMMA*G + GAMMA
#define WS_Z0 8192    // 64*16 initial Ztilde = hs@w1 + b1

typedef float v2f __attribute__((ext_vector_type(2)));
typedef unsigned int v2u __attribute__((ext_vector_type(2)));

template<int CTRL>
__device__ __forceinline__ float dppmov(float x) {
    return __int_as_float(__builtin_amdgcn_update_dpp(0, __float_as_int(x), CTRL, 0xF, 0xF, true));
}
__device__ __forceinline__ v2u swap16(float a, float b) {
    return __builtin_amdgcn_permlane16_swap(__float_as_uint(a), __float_as_uint(b), false, false);
}
__device__ __forceinline__ v2u swap32(float a, float b) {
    return __builtin_amdgcn_permlane32_swap(__float_as_uint(a), __float_as_uint(b), false, false);
}
#define U2F(x) __uint_as_float(x)

// ---------------- kernel A: hs table (per-token embed->FFN->LN), 64 blocks ----------------
__global__ void hs_kernel(const float* __restrict__ embed,
                          const float* __restrict__ ffw1, const float* __restrict__ ffb1,
                          const float* __restrict__ ffw2, const float* __restrict__ ffb2,
                          const float* __restrict__ lng,  const float* __restrict__ lnb,
                          float* __restrict__ ws) {
    __shared__ float e[64];
    __shared__ float a1[128];
    int w = blockIdx.x;
    int tid = threadIdx.x;
    if (tid < 64) e[tid] = embed[w * 64 + tid];
    __syncthreads();
    float z1 = ffb1[tid];
    for (int x = 0; x < 64; ++x) z1 += e[x] * ffw1[x * 128 + tid];
    a1[tid] = fmaxf(z1, 0.0f);
    __syncthreads();
    if (tid < 64) {
        float f = ffb2[tid];
        for (int i = 0; i < 128; ++i) f += a1[i] * ffw2[i * 64 + tid];
        float hv = e[tid] + f;
        float s = hv;
#pragma unroll
        for (int m = 32; m >= 1; m >>= 1) s += __shfl_xor(s, m);
        float mu = s * (1.0f / 64.0f);
        float dv = hv - mu;
        float vs = dv * dv;
#pragma unroll
        for (int m = 32; m >= 1; m >>= 1) vs += __shfl_xor(vs, m);
        float rstd = 1.0f / sqrtf(vs * (1.0f / 64.0f) + EPSV);
        ws[WS_HS + w * 64 + tid] = dv * rstd * lng[tid] + lnb[tid];
    }
}

// ---------------- kernel B: pre-scaled Gram + Ztilde0, 64 blocks ----------------
__global__ void gz_kernel(const float* __restrict__ w1, const float* __restrict__ b1,
                          float* __restrict__ ws) {
    __shared__ float row[64];
    int w = blockIdx.x, tid = threadIdx.x;
    row[tid] = ws[WS_HS + w * 64 + tid];
    __syncthreads();
    float g = 0.0f;
    for (int x = 0; x < 64; ++x) g += row[x] * ws[WS_HS + tid * 64 + x];
    ws[WS_G + w * 64 + tid] = GAMMA * g + GAMMA;      // pre-scaled
    if (tid < 16) {
        float z = b1[tid];
        for (int x = 0; x < 64; ++x) z += row[x] * w1[x * 16 + tid];
        ws[WS_Z0 + w * 16 + tid] = z;
    }
}

// scalar view of packed v2f array
#define PV(arr, j) (((j) & 1) ? arr[(j) >> 1].y : arr[(j) >> 1].x)

// ---------------- main kernel: per-batch sequential TTT scan (R11/R16, measured optimum) ----------------
// one wave per batch; XOR-permuted slot layout (P = 8*b0 + 4*b1, chunk xor
// K = 2*b0 + b1); ALL loop-resident data in LDS (no SMEM in the loop -- R10
// showed s_load shares lgkmcnt with DS and forces conservative waits, +40us).
// Reduction: select-free quad_perm folds -> mask -> row_ror:4/8 ->
// permlane16/32 pair-swap combine -> swap re-replicate -> quad_perm bcast.
// Full unmasked Z writeback: R15 proved its bank conflicts are 100% hidden.
// Separate wide prep kernels: R9/R15/R17 fusion attempts all slower.
struct TTTSmem {
    float hs[4096];
    float Gs[4096];
    int   sq[2048];               // unguarded prefetch reads sq[2048..2049] -> lands in Z[0..1] (harmless)
    __align__(16) float Z[64 * 20 + 8];
    float ctx[64];
};

__launch_bounds__(64, 1)
__global__ void ttt_kernel(const int* __restrict__ seq,
                           const float* __restrict__ w2, const float* __restrict__ b2i,
                           const float* __restrict__ outw, const float* __restrict__ outb,
                           const float* __restrict__ ws, float* __restrict__ out) {
    __shared__ TTTSmem sm;

    const int b    = blockIdx.x;
    const int lane = threadIdx.x;

    const int P = ((lane & 1) << 3) | ((lane & 2) << 1);   // 8*b0 + 4*b1
    const int K = ((lane & 1) << 1) | ((lane >> 1) & 1);   // 2*b0 + b1 (chunk xor)
    const int ro0 = (0 ^ K) << 2;
    const int ro1 = (1 ^ K) << 2;
    const int ro2 = (2 ^ K) << 2;
    const int ro3 = (3 ^ K) << 2;

    {   // vectorized staging
        float4*       hv = (float4*)sm.hs;
        const float4* sv = (const float4*)(ws + WS_HS);
#pragma unroll
        for (int m = 0; m < 16; ++m) hv[m * 64 + lane] = sv[m * 64 + lane];
        float4*       gv = (float4*)sm.Gs;
        const float4* gs = (const float4*)(ws + WS_G);
#pragma unroll
        for (int m = 0; m < 16; ++m) gv[m * 64 + lane] = gs[m * 64 + lane];
        int4*       qv = (int4*)sm.sq;
        const int4* qs = (const int4*)(seq + b * 2048);
#pragma unroll
        for (int m = 0; m < 8; ++m) qv[m * 64 + lane] = qs[m * 64 + lane];
        const float4* z0 = (const float4*)(ws + WS_Z0 + lane * 16);
        float4* zr = (float4*)(sm.Z + lane * 20);
        zr[0] = z0[0]; zr[1] = z0[1]; zr[2] = z0[2]; zr[3] = z0[3];
    }

    // W2 in permuted slot order: slot s <- logical s ^ P
    v2f W2p[8], z2[8];
#pragma unroll
    for (int i = 0; i < 8; ++i) {
        const int m = (2 * i) ^ P;
        v2f w;
        w.x = w2[m * 64 + lane];
        w.y = w2[(m + 1) * 64 + lane];
        W2p[i] = w;
    }
    float b2v = b2i[lane];
    __syncthreads();

    // Zr = permuted read of own row (as float4 chunks); z2 = permuted read of row tk0
    float4 ZrQ[4];
    v2f* Zv = (v2f*)ZrQ;
    {
        const float* zb = sm.Z + lane * 20;
        ZrQ[0] = *(const float4*)(zb + ro0);
        ZrQ[1] = *(const float4*)(zb + ro1);
        ZrQ[2] = *(const float4*)(zb + ro2);
        ZrQ[3] = *(const float4*)(zb + ro3);
    }
    int tk = sm.sq[0];
    {
        const float* zb = sm.Z + tk * 20;
        const float4 c0 = *(const float4*)(zb + ro0);
        const float4 c1 = *(const float4*)(zb + ro1);
        const float4 c2 = *(const float4*)(zb + ro2);
        const float4 c3 = *(const float4*)(zb + ro3);
        z2[0] = {c0.x, c0.y}; z2[1] = {c0.z, c0.w};
        z2[2] = {c1.x, c1.y}; z2[3] = {c1.z, c1.w};
        z2[4] = {c2.x, c2.y}; z2[5] = {c2.z, c2.w};
        z2[6] = {c3.x, c3.y}; z2[7] = {c3.z, c3.w};
    }
    float vv = sm.hs[sm.sq[1] * 64 + lane];

    float4* const wp0 = (float4*)(sm.Z + lane * 20 + ro0);
    float4* const wp1 = (float4*)(sm.Z + lane * 20 + ro1);
    float4* const wp2 = (float4*)(sm.Z + lane * 20 + ro2);
    float4* const wp3 = (float4*)(sm.Z + lane * 20 + ro3);

    int2 pairT  = *(const int2*)(sm.sq + 2);
    int2 pairT1 = *(const int2*)(sm.sq + 4);

    // main loop: steps 0..1021 (last step peeled)
#pragma unroll 2
    for (int t = 0; t < TSTEPS - 1; ++t) {
        const int tkn = pairT.x;
        const int tvn = pairT.y;

        // ---- DS reads (reg addresses, consumed late) ----
        const float* zb = sm.Z + tkn * 20;
        const float4 e0 = *(const float4*)(zb + ro0);
        const float4 e1 = *(const float4*)(zb + ro1);
        const float4 e2 = *(const float4*)(zb + ro2);
        const float4 e3 = *(const float4*)(zb + ro3);
        const float vnext = sm.hs[tvn * 64 + lane];
        const float cr = sm.Gs[tk * 64 + lane];     // pre-scaled: gamma*(G+1)
        const float cz = sm.Gs[tk * 64 + tkn];
        const int2 pairT2 = *(const int2*)(sm.sq + 2 * t + 6);  // t=1021 reads Z[0..1]: unused

        // ---- forward ----
        const v2f zero2 = {0.0f, 0.0f};
        v2f a2[8];
#pragma unroll
        for (int i = 0; i < 8; ++i) a2[i] = __builtin_elementwise_max(z2[i], zero2);
        v2f acc0 = a2[0] * W2p[0] + a2[1] * W2p[1];
        v2f acc1 = a2[2] * W2p[2] + a2[3] * W2p[3];
        v2f acc2 = a2[4] * W2p[4] + a2[5] * W2p[5];
        v2f acc3 = a2[6] * W2p[6] + a2[7] * W2p[7];
        v2f accv = (acc0 + acc1) + (acc2 + acc3);
        const float y = b2v + accv.x + accv.y;
        const float d = y - vv;

        // ---- p (pre-update W2) + local W2/b2 update ----
        const v2f d2 = {d, d};
        v2f p2[8];
#pragma unroll
        for (int i = 0; i < 8; ++i) p2[i] = W2p[i] * d2;
        const float sd = GAMMA * d;
        const v2f sd2 = {sd, sd};
        b2v -= sd;
#pragma unroll
        for (int i = 0; i < 8; ++i) W2p[i] = W2p[i] - sd2 * a2[i];

        // ---- reduction: select-free folds over lane bits 0,1 ----
        float q[8];
#pragma unroll
        for (int j = 0; j < 8; ++j)
            q[j] = PV(p2, j) + dppmov<0xB1>(PV(p2, j + 8));
        float r[4];
#pragma unroll
        for (int j = 0; j < 4; ++j)
            r[j] = q[j] + dppmov<0x4E>(q[j + 4]);

        // ---- mask at r (slot-aligned; commutes with the orbit sums) ----
        float rm[4];
        rm[0] = (a2[0].x > 0.0f) ? r[0] : 0.0f;
        rm[1] = (a2[0].y > 0.0f) ? r[1] : 0.0f;
        rm[2] = (a2[1].x > 0.0f) ? r[2] : 0.0f;
        rm[3] = (a2[1].y > 0.0f) ? r[3] : 0.0f;

        // ---- orbit sums over lane bits 2,3 ----
#pragma unroll
        for (int j = 0; j < 4; ++j) {
            rm[j] = rm[j] + dppmov<0x124>(rm[j]);   // row_ror:4
            rm[j] = rm[j] + dppmov<0x128>(rm[j]);   // row_ror:8
        }

        // ---- pair-swap combine over bits 4,5 then re-replicate ----
        v2u f01 = swap16(rm[0], rm[1]);
        const float F  = U2F(f01[0]) + U2F(f01[1]);
        v2u f23 = swap16(rm[2], rm[3]);
        const float F2 = U2F(f23[0]) + U2F(f23[1]);
        v2u g01 = swap32(F, F2);
        const float T  = U2F(g01[0]) + U2F(g01[1]);
        v2u u01 = swap16(T, T);
        const float U0 = U2F(u01[0]);
        const float U1 = U2F(u01[1]);
        v2u v02 = swap32(U0, U0);
        v2u v13 = swap32(U1, U1);
        const float D0 = U2F(v02[0]);
        const float D2 = U2F(v02[1]);
        const float D1 = U2F(v13[0]);
        const float D3 = U2F(v13[1]);

        // ---- broadcast into permuted slots: slots 0-3 identity, rest XOR quad_perms ----
        float dzs[16];
        dzs[0] = D0; dzs[1] = D1; dzs[2] = D2; dzs[3] = D3;
        dzs[4]  = dppmov<0x4E>(D0); dzs[5]  = dppmov<0x4E>(D1);
        dzs[6]  = dppmov<0x4E>(D2); dzs[7]  = dppmov<0x4E>(D3);
        dzs[8]  = dppmov<0xB1>(D0); dzs[9]  = dppmov<0xB1>(D1);
        dzs[10] = dppmov<0xB1>(D2); dzs[11] = dppmov<0xB1>(D3);
        dzs[12] = dppmov<0x1B>(D0); dzs[13] = dppmov<0x1B>(D1);
        dzs[14] = dppmov<0x1B>(D2); dzs[15] = dppmov<0x1B>(D3);

        v2f dz2[8];
#pragma unroll
        for (int i = 0; i < 8; ++i) dz2[i] = {dzs[2 * i], dzs[2 * i + 1]};

        // ---- apply ----
        const v2f cr2 = {cr, cr}, cz2 = {cz, cz};
        const v2f zq2[8] = { {e0.x, e0.y}, {e0.z, e0.w}, {e1.x, e1.y}, {e1.z, e1.w},
                             {e2.x, e2.y}, {e2.z, e2.w}, {e3.x, e3.y}, {e3.z, e3.w} };
#pragma unroll
        for (int i = 0; i < 8; ++i) {
            Zv[i]  = Zv[i]  - cr2 * dz2[i];
            z2[i]  = zq2[i] - cz2 * dz2[i];
        }
        *wp0 = ZrQ[0];
        *wp1 = ZrQ[1];
        *wp2 = ZrQ[2];
        *wp3 = ZrQ[3];

        vv = vnext;
        tk = tkn;
        pairT = pairT1;
        pairT1 = pairT2;
    }

    // ---- peeled final step (t = 1022): tkn = query token sq[2047] ----
    {
        const int tkn = pairT.y;                  // pairT = {sq[2046], sq[2047]}
        const float* zb = sm.Z + tkn * 20;
        const float4 e0 = *(const float4*)(zb + ro0);
        const float4 e1 = *(const float4*)(zb + ro1);
        const float4 e2 = *(const float4*)(zb + ro2);
        const float4 e3 = *(const float4*)(zb + ro3);
        const float cz = sm.Gs[tk * 64 + tkn];

        const v2f zero2 = {0.0f, 0.0f};
        v2f a2[8];
#pragma unroll
        for (int i = 0; i < 8; ++i) a2[i] = __builtin_elementwise_max(z2[i], zero2);
        v2f acc0 = a2[0] * W2p[0] + a2[1] * W2p[1];
        v2f acc1 = a2[2] * W2p[2] + a2[3] * W2p[3];
        v2f acc2 = a2[4] * W2p[4] + a2[5] * W2p[5];
        v2f acc3 = a2[6] * W2p[6] + a2[7] * W2p[7];
        v2f accv = (acc0 + acc1) + (acc2 + acc3);
        const float y = b2v + accv.x + accv.y;
        const float d = y - vv;

        const v2f d2 = {d, d};
        v2f p2[8];
#pragma unroll
        for (int i = 0; i < 8; ++i) p2[i] = W2p[i] * d2;
        const float sd = GAMMA * d;
        const v2f sd2 = {sd, sd};
        b2v -= sd;
#pragma unroll
        for (int i = 0; i < 8; ++i) W2p[i] = W2p[i] - sd2 * a2[i];

        float q[8];
#pragma unroll
        for (int j = 0; j < 8; ++j)
            q[j] = PV(p2, j) + dppmov<0xB1>(PV(p2, j + 8));
        float r[4];
#pragma unroll
        for (int j = 0; j < 4; ++j)
            r[j] = q[j] + dppmov<0x4E>(q[j + 4]);
        float rm[4];
        rm[0] = (a2[0].x > 0.0f) ? r[0] : 0.0f;
        rm[1] = (a2[0].y > 0.0f) ? r[1] : 0.0f;
        rm[2] = (a2[1].x > 0.0f) ? r[2] : 0.0f;
        rm[3] = (a2[1].y > 0.0f) ? r[3] : 0.0f;
#pragma unroll
        for (int j = 0; j < 4; ++j) {
            rm[j] = rm[j] + dppmov<0x124>(rm[j]);
            rm[j] = rm[j] + dppmov<0x128>(rm[j]);
        }
        v2u f01 = swap16(rm[0], rm[1]);
        const float F  = U2F(f01[0]) + U2F(f01[1]);
        v2u f23 = swap16(rm[2], rm[3]);
        const float F2 = U2F(f23[0]) + U2F(f23[1]);
        v2u g01 = swap32(F, F2);
        const float T  = U2F(g01[0]) + U2F(g01[1]);
        v2u u01 = swap16(T, T);
        const float U0 = U2F(u01[0]);
        const float U1 = U2F(u01[1]);
        v2u v02 = swap32(U0, U0);
        v2u v13 = swap32(U1, U1);
        const float D0 = U2F(v02[0]);
        const float D2 = U2F(v02[1]);
        const float D1 = U2F(v13[0]);
        const float D3 = U2F(v13[1]);

        float dzs[16];
        dzs[0] = D0; dzs[1] = D1; dzs[2] = D2; dzs[3] = D3;
        dzs[4]  = dppmov<0x4E>(D0); dzs[5]  = dppmov<0x4E>(D1);
        dzs[6]  = dppmov<0x4E>(D2); dzs[7]  = dppmov<0x4E>(D3);
        dzs[8]  = dppmov<0xB1>(D0); dzs[9]  = dppmov<0xB1>(D1);
        dzs[10] = dppmov<0xB1>(D2); dzs[11] = dppmov<0xB1>(D3);
        dzs[12] = dppmov<0x1B>(D0); dzs[13] = dppmov<0x1B>(D1);
        dzs[14] = dppmov<0x1B>(D2); dzs[15] = dppmov<0x1B>(D3);

        const v2f cz2 = {cz, cz};
        const v2f zq2[8] = { {e0.x, e0.y}, {e0.z, e0.w}, {e1.x, e1.y}, {e1.z, e1.w},
                             {e2.x, e2.y}, {e2.z, e2.w}, {e3.x, e3.y}, {e3.z, e3.w} };
#pragma unroll
        for (int i = 0; i < 8; ++i) {
            v2f dzi = {dzs[2 * i], dzs[2 * i + 1]};
            z2[i] = zq2[i] - cz2 * dzi;
        }
    }

    // ---- final eval: ctx = relu(z_final)@W2_f + b2_f (order-free sum) ----
    {
        const v2f zero2 = {0.0f, 0.0f};
        v2f acc = {0.0f, 0.0f};
#pragma unroll
        for (int i = 0; i < 8; ++i)
            acc = acc + __builtin_elementwise_max(z2[i], zero2) * W2p[i];
        sm.ctx[lane] = b2v + acc.x + acc.y;
    }
    __syncthreads();

    float o = outb[lane];
    for (int hh = 0; hh < 64; ++hh) o += sm.ctx[hh] * outw[hh * 64 + lane];
    out[b * 64 + lane] = o;
}

// ---------------- launcher ----------------
extern "C" void kernel_launch(void* const* d_in, const int* in_sizes, int n_in,
                              void* d_out, int out_size, void* d_ws, size_t ws_size,
                              hipStream_t stream) {
    const int*   seq   = (const int*)d_in[0];
    const float* embed = (const float*)d_in[1];
    const float* ffw1  = (const float*)d_in[2];
    const float* ffb1  = (const float*)d_in[3];
    const float* ffw2  = (const float*)d_in[4];
    const float* ffb2  = (const float*)d_in[5];
    const float* lng   = (const float*)d_in[6];
    const float* lnb   = (const float*)d_in[7];
    const float* w1    = (const float*)d_in[8];
    const float* b1    = (const float*)d_in[9];
    const float* w2    = (const float*)d_in[10];
    const float* b2    = (const float*)d_in[11];
    const float* outw  = (const float*)d_in[12];
    const float* outb  = (const float*)d_in[13];
    float* ws  = (float*)d_ws;
    float* out = (float*)d_out;

    hipLaunchKernelGGL(hs_kernel, dim3(64), dim3(128), 0, stream,
                       embed, ffw1, ffb1, ffw2, ffb2, lng, lnb, ws);
    hipLaunchKernelGGL(gz_kernel, dim3(64), dim3(64), 0, stream, w1, b1, ws);
    hipLaunchKernelGGL(ttt_kernel, dim3(256), dim3(64), 0, stream,
                       seq, w2, b2, outw, outb, ws, out);
}